// Round 5
// baseline (30.688 us; speedup 1.0000x reference)
//
#include <hip/hip_runtime.h>
#include <hip/hip_bf16.h>

// GraphSage fused single-kernel: gather + mean + [agg|xs]·[W;b] bf16-MFMA + ReLU
// adj (16,32,32,16) i32; emb (1000001,128) f32; W,b (128,128) f32
// out (16,32,32,128) f32.  16384 rows, 16 rows/block, 1024 blocks x 512 thr.
// Gather split across 2 half-waves per (row,chunk) for 2x in-flight loads.

constexpr int DIM   = 128;
constexpr int KN    = 16;
constexpr int RPB   = 16;
constexpr int NROWS = 16 * 32 * 32;      // 16384
constexpr int LDA   = 264;               // shorts per LDS A-row (256 + 8 pad)

typedef __bf16 bf16x8 __attribute__((ext_vector_type(8)));
typedef float  f32x4  __attribute__((ext_vector_type(4)));

__device__ __forceinline__ unsigned short f2b(float x) {
    __bf16 h = (__bf16)x;                 // RTNE
    return __builtin_bit_cast(unsigned short, h);
}

__global__ __launch_bounds__(512, 4)     // 8 waves/block, 2 blocks/CU
void graphsage_mfma(const int* __restrict__ adj,
                    const float* __restrict__ emb,
                    const float* __restrict__ W,
                    const float* __restrict__ Bm,
                    float* __restrict__ out)
{
    __shared__ unsigned short ldsA[RPB * LDA];   // 16 x 264 shorts = 8.25 KB
    __shared__ int idx_lds[RPB * KN];

    const int t    = threadIdx.x;
    const int row0 = blockIdx.x * RPB;

    if (t < RPB * KN) idx_lds[t] = adj[row0 * KN + t];
    __syncthreads();

    // ---- Phase A: gather + mean (2 lanes per row-chunk, 8 neighbors each) ----
    {
        const int r     = t >> 5;         // 0..15
        const int c16   = t & 15;         // 16B-chunk index
        const int half  = (t >> 4) & 1;   // neighbor half
        const int dbase = c16 * 8;
        float4 x0 = make_float4(0.f,0.f,0.f,0.f), x1 = make_float4(0.f,0.f,0.f,0.f);
        float4 a0 = make_float4(0.f,0.f,0.f,0.f), a1 = make_float4(0.f,0.f,0.f,0.f);
        #pragma unroll
        for (int k = 0; k < 8; ++k) {
            const int kk = half * 8 + k;
            const int e  = idx_lds[r * KN + kk];
            const float4* p =
                reinterpret_cast<const float4*>(emb + (size_t)e * DIM + dbase);
            const float4 v0 = p[0];
            const float4 v1 = p[1];
            if (half == 0 && k == 0) { x0 = v0; x1 = v1; }   // self row
            else {
                a0.x += v0.x; a0.y += v0.y; a0.z += v0.z; a0.w += v0.w;
                a1.x += v1.x; a1.y += v1.y; a1.z += v1.z; a1.w += v1.w;
            }
        }
        // cross-half reduce: lane l <-> l^16 hold partials of the same chunk
        #pragma unroll
        for (int j = 0; j < 4; ++j) {
            (&a0.x)[j] += __shfl_xor((&a0.x)[j], 16, 64);
            (&a1.x)[j] += __shfl_xor((&a1.x)[j], 16, 64);
        }
        if (half == 0) {
            const float s = 1.0f / 15.0f;
            union { unsigned short u[8]; uint4 q; } pa, px;
            pa.u[0] = f2b(a0.x * s); pa.u[1] = f2b(a0.y * s);
            pa.u[2] = f2b(a0.z * s); pa.u[3] = f2b(a0.w * s);
            pa.u[4] = f2b(a1.x * s); pa.u[5] = f2b(a1.y * s);
            pa.u[6] = f2b(a1.z * s); pa.u[7] = f2b(a1.w * s);
            px.u[0] = f2b(x0.x); px.u[1] = f2b(x0.y);
            px.u[2] = f2b(x0.z); px.u[3] = f2b(x0.w);
            px.u[4] = f2b(x1.x); px.u[5] = f2b(x1.y);
            px.u[6] = f2b(x1.z); px.u[7] = f2b(x1.w);
            // k-space: [0..127] = agg (·W), [128..255] = x_self (·b)
            *reinterpret_cast<uint4*>(&ldsA[r * LDA + c16 * 8])        = pa.q;
            *reinterpret_cast<uint4*>(&ldsA[r * LDA + (16 + c16) * 8]) = px.q;
        }
    }
    __syncthreads();

    // ---- Phase B: MFMA.  8 waves, wave w -> cols [16w, 16w+16) ----
    {
        const int wid  = t >> 6;
        const int lane = t & 63;
        const int col  = lane & 15;
        const int g    = lane >> 4;          // k-group within 32-k MFMA step
        const int n0   = wid * 16;

        f32x4 acc = {0.f, 0.f, 0.f, 0.f};
        const int arow = lane & 15;

        #pragma unroll
        for (int s = 0; s < 8; ++s) {
            const int c = s * 4 + g;         // 16B chunk: k = s*32 + g*8
            bf16x8 a = __builtin_bit_cast(bf16x8,
                *reinterpret_cast<const uint4*>(&ldsA[arow * LDA + c * 8]));
            // B operand from global fp32 (L2-resident), convert in-register.
            const float* __restrict__ M = (s < 4) ? W : Bm;
            const int k0 = (s & 3) * 32 + g * 8;
            union { unsigned short u[8]; bf16x8 v; } bu;
            #pragma unroll
            for (int j = 0; j < 8; ++j) {
                bu.u[j] = f2b(M[(size_t)(k0 + j) * DIM + n0 + col]);
            }
            acc = __builtin_amdgcn_mfma_f32_16x16x32_bf16(a, bu.v, acc, 0, 0, 0);
        }

        // D layout: col = lane&15, row = (lane>>4)*4 + reg
        #pragma unroll
        for (int reg = 0; reg < 4; ++reg) {
            const int rr = g * 4 + reg;
            out[(size_t)(row0 + rr) * DIM + n0 + col] = fmaxf(acc[reg], 0.0f);
        }
    }
}

extern "C" void kernel_launch(void* const* d_in, const int* in_sizes, int n_in,
                              void* d_out, int out_size, void* d_ws, size_t ws_size,
                              hipStream_t stream) {
    const int*   adj = (const int*)  d_in[0];
    const float* emb = (const float*)d_in[1];
    const float* W   = (const float*)d_in[2];
    const float* b   = (const float*)d_in[3];
    float*       out = (float*)d_out;

    graphsage_mfma<<<dim3(NROWS / RPB), dim3(512), 0, stream>>>(adj, emb, W, b, out);
}

// Round 6
// 28.127 us; speedup vs baseline: 1.0911x; 1.0911x over previous
//
#include <hip/hip_runtime.h>
#include <hip/hip_bf16.h>

// GraphSage fused single-kernel: gather + mean + [agg|xs]·[W;b] bf16-MFMA + ReLU
// adj (16,32,32,16) i32; emb (1000001,128) f32; W,b (128,128) f32
// out (16,32,32,128) f32.  Rows = 16384, 16 rows/block, 1024 blocks.
// B-operands converted fp32->bf16 in-register per wave (no prep kernel, no ws).
// Round-4 configuration (best: 28.3 us) — gather is DRAM-random-BW-bound.

constexpr int DIM   = 128;
constexpr int KN    = 16;
constexpr int RPB   = 16;
constexpr int NROWS = 16 * 32 * 32;      // 16384
constexpr int LDA   = 264;               // shorts per LDS A-row (256 + 8 pad)

typedef __bf16 bf16x8 __attribute__((ext_vector_type(8)));
typedef float  f32x4  __attribute__((ext_vector_type(4)));

__device__ __forceinline__ unsigned short f2b(float x) {
    __bf16 h = (__bf16)x;                 // RTNE
    return __builtin_bit_cast(unsigned short, h);
}

__global__ __launch_bounds__(256, 4)
void graphsage_mfma(const int* __restrict__ adj,
                    const float* __restrict__ emb,
                    const float* __restrict__ W,
                    const float* __restrict__ Bm,
                    float* __restrict__ out)
{
    __shared__ unsigned short ldsA[RPB * LDA];   // 16 x 264 shorts = 8.25 KB
    __shared__ int idx_lds[RPB * KN];

    const int t    = threadIdx.x;
    const int row0 = blockIdx.x * RPB;

    idx_lds[t] = adj[row0 * KN + t];
    __syncthreads();

    // ---- Phase A: gather + mean, convert to bf16, store A-tile ----
    {
        const int r     = t >> 4;
        const int c16   = t & 15;
        const int dbase = c16 * 8;
        float4 x0, x1;
        float4 a0 = make_float4(0.f, 0.f, 0.f, 0.f);
        float4 a1 = make_float4(0.f, 0.f, 0.f, 0.f);
        #pragma unroll
        for (int k = 0; k < KN; ++k) {
            const int e = idx_lds[r * KN + k];
            const float4* p =
                reinterpret_cast<const float4*>(emb + (size_t)e * DIM + dbase);
            const float4 v0 = p[0];
            const float4 v1 = p[1];
            if (k == 0) { x0 = v0; x1 = v1; }
            else {
                a0.x += v0.x; a0.y += v0.y; a0.z += v0.z; a0.w += v0.w;
                a1.x += v1.x; a1.y += v1.y; a1.z += v1.z; a1.w += v1.w;
            }
        }
        const float s = 1.0f / 15.0f;
        union { unsigned short u[8]; uint4 q; } pa, px;
        pa.u[0] = f2b(a0.x * s); pa.u[1] = f2b(a0.y * s);
        pa.u[2] = f2b(a0.z * s); pa.u[3] = f2b(a0.w * s);
        pa.u[4] = f2b(a1.x * s); pa.u[5] = f2b(a1.y * s);
        pa.u[6] = f2b(a1.z * s); pa.u[7] = f2b(a1.w * s);
        px.u[0] = f2b(x0.x); px.u[1] = f2b(x0.y);
        px.u[2] = f2b(x0.z); px.u[3] = f2b(x0.w);
        px.u[4] = f2b(x1.x); px.u[5] = f2b(x1.y);
        px.u[6] = f2b(x1.z); px.u[7] = f2b(x1.w);
        // k-space: [0..127] = agg (·W), [128..255] = x_self (·b)
        *reinterpret_cast<uint4*>(&ldsA[r * LDA + c16 * 8])        = pa.q;
        *reinterpret_cast<uint4*>(&ldsA[r * LDA + (16 + c16) * 8]) = px.q;
    }
    __syncthreads();

    // ---- Phase B: MFMA.  wave w -> cols [32w, 32w+32) ----
    {
        const int wid  = t >> 6;
        const int lane = t & 63;
        const int col  = lane & 15;
        const int g    = lane >> 4;          // k-group within 32-k MFMA step
        const int n0   = wid * 32;

        f32x4 acc0 = {0.f, 0.f, 0.f, 0.f};
        f32x4 acc1 = {0.f, 0.f, 0.f, 0.f};
        const int arow = lane & 15;

        #pragma unroll
        for (int s = 0; s < 8; ++s) {
            const int c = s * 4 + g;         // 16B chunk: k = s*32 + g*8
            bf16x8 a = __builtin_bit_cast(bf16x8,
                *reinterpret_cast<const uint4*>(&ldsA[arow * LDA + c * 8]));
            // B operand from global fp32 (L2-resident), convert in-register.
            // k-space s<4 -> W (agg half), s>=4 -> b (x_self half).
            const float* __restrict__ M = (s < 4) ? W : Bm;
            const int k0 = (s & 3) * 32 + g * 8;
            union { unsigned short u[8]; bf16x8 v; } b0u, b1u;
            #pragma unroll
            for (int j = 0; j < 8; ++j) {
                const float* rowp = M + (size_t)(k0 + j) * DIM + n0;
                b0u.u[j] = f2b(rowp[col]);
                b1u.u[j] = f2b(rowp[16 + col]);
            }
            acc0 = __builtin_amdgcn_mfma_f32_16x16x32_bf16(a, b0u.v, acc0, 0, 0, 0);
            acc1 = __builtin_amdgcn_mfma_f32_16x16x32_bf16(a, b1u.v, acc1, 0, 0, 0);
        }

        // D layout: col = lane&15, row = (lane>>4)*4 + reg
        #pragma unroll
        for (int reg = 0; reg < 4; ++reg) {
            const int rr = g * 4 + reg;
            float* o = out + (size_t)(row0 + rr) * DIM;
            o[n0 + col]      = fmaxf(acc0[reg], 0.0f);
            o[n0 + 16 + col] = fmaxf(acc1[reg], 0.0f);
        }
    }
}

extern "C" void kernel_launch(void* const* d_in, const int* in_sizes, int n_in,
                              void* d_out, int out_size, void* d_ws, size_t ws_size,
                              hipStream_t stream) {
    const int*   adj = (const int*)  d_in[0];
    const float* emb = (const float*)d_in[1];
    const float* W   = (const float*)d_in[2];
    const float* b   = (const float*)d_in[3];
    float*       out = (float*)d_out;

    graphsage_mfma<<<dim3(NROWS / RPB), dim3(256), 0, stream>>>(adj, emb, W, b, out);
}